// Round 7
// baseline (195.245 us; speedup 1.0000x reference)
//
#include <hip/hip_runtime.h>
#include <stdint.h>

#pragma clang fp contract(off)   // pin IEEE single-rounding: must match numpy ref bit-exactly

#define BATCH 4
#define N1 25200
#define NROW 50400           // N1 + N2
#define NCLS 100
#define TOT (BATCH*NROW)     // 201600
#define CAPB 2048            // per-(batch,class) capacity (x2 classes ~1260 expected)
#define SCORE_T 0.25f
#define IOU_T 0.45f
#define MAXWH 7680.0f

#define X1_SLAB 64
#define X1_SPB 394           // ceil(25200/64)
#define X2_SLAB 256
#define X2_SPB 99            // ceil(25200/256)

typedef unsigned long long u64;

// key = score_bits(63..32) | (n^0xFFFF)(23..8) | catid(7..0)
// descending key order == (score desc, n asc); catid below n never decides
__device__ __forceinline__ u64 pack_key(unsigned sb, int n, int cid) {
    return ((u64)sb << 32) | ((u64)(unsigned)((n ^ 0xFFFF) & 0xFFFF) << 8) | (u64)(unsigned)cid;
}

// ---------------- Kernel A: decode + argmax -> boxes4 + one packed key per row.
__global__ __launch_bounds__(256) void k_rows(const float* __restrict__ x1,
                                              const float* __restrict__ x2,
                                              float4* __restrict__ boxes4,
                                              u64* __restrict__ rowKey) {
    __shared__ float4 ld4[1600];          // 25.6 KB (>= 64*85 and 256*25 floats)
    float* ld = (float*)ld4;
    int blk = blockIdx.x;
    int t = threadIdx.x;
    const int NX1 = BATCH * X1_SPB;
    if (blk < NX1) {
        int b = blk / X1_SPB, s = blk - b * X1_SPB;
        int r0 = s * X1_SLAB;
        int nr = min(X1_SLAB, N1 - r0);
        const float4* src = (const float4*)(x1 + ((size_t)b * N1 + r0) * 85);
        int count4 = (nr * 85) >> 2;      // nr in {64,48} -> divisible by 4
        for (int i = t; i < count4; i += 256) ld4[i] = src[i];
        __syncthreads();
        int row = t >> 2, sub = t & 3;
        if (row < nr) {
            const float* p = ld + row * 85;
            float conf = p[4];
            u64 key = 0ULL;
            int base = sub * 20;
            for (int c = 0; c < 20; ++c) {
                int j = base + c;
                float v = p[5 + j] * conf;
                u64 kk = ((u64)__float_as_uint(v) << 32) | (unsigned)~(unsigned)j;
                if (kk > key) key = kk;
            }
            u64 o;
            o = __shfl_xor(key, 1, 64); if (o > key) key = o;
            o = __shfl_xor(key, 2, 64); if (o > key) key = o;
            if (sub == 0) {
                float best = __uint_as_float((unsigned)(key >> 32));
                int bestj = ~(unsigned)key;
                int n = r0 + row;
                int r = b * NROW + n;
                u64 outk = 0ULL;
                if (best >= SCORE_T) {
                    float cx = p[0], cy = p[1], w = p[2], h = p[3];
                    boxes4[r] = make_float4(cx - 0.5f * w, cy - 0.5f * h,
                                            cx + 0.5f * w, cy + 0.5f * h);
                    outk = pack_key((unsigned)(key >> 32), n, bestj);
                }
                rowKey[r] = outk;         // every row written (no stale poison)
            }
        }
    } else {
        int blk2 = blk - NX1;
        int b = blk2 / X2_SPB, s = blk2 - b * X2_SPB;
        int r0 = s * X2_SLAB;
        int nr = min(X2_SLAB, N1 - r0);
        const float4* src = (const float4*)(x2 + ((size_t)b * N1 + r0) * 25);
        int count4 = (nr * 25) >> 2;      // nr in {256,112} -> divisible by 4
        for (int i = t; i < count4; i += 256) ld4[i] = src[i];
        __syncthreads();
        if (t < nr) {
            const float* p = ld + t * 25;
            float conf = p[4];
            float best = 0.0f; int bestj = 0;   // padded classes 0..79 exact zeros
            for (int j2 = 0; j2 < 20; ++j2) {
                float v = p[5 + j2] * conf;
                if (v > best) { best = v; bestj = 80 + j2; }
            }
            int n = N1 + r0 + t;
            int r = b * NROW + n;
            u64 outk = 0ULL;
            if (best >= SCORE_T) {
                float cx = p[0], cy = p[1], w = p[2], h = p[3];
                boxes4[r] = make_float4(cx - 0.5f * w, cy - 0.5f * h,
                                        cx + 0.5f * w, cy + 0.5f * h);
                outk = pack_key(__float_as_uint(best), n, bestj);
            }
            rowKey[r] = outk;
        }
    }
}

// ---------------- Kernel C: per-bucket compact + sort + 4-wave chunked greedy.
// 256-candidate chunks: suppress-vs-accepted sweep runs once per 256 (all 4
// waves in parallel, float4 broadcast reads); waves then resolve in order.
__global__ __launch_bounds__(256) void k_nms(const float4* __restrict__ boxes4,
                                             const u64* __restrict__ rowKey,
                                             u64* __restrict__ accKey,
                                             int* __restrict__ accCnt) {
    __shared__ u64 sk[CAPB];              // 16 KB
    __shared__ float4 cQ[CAPB];           // 32 KB, quantized boxes AoS
    __shared__ float4 accQ[100];          // accepted boxes
    __shared__ int lcnt;
    __shared__ int mSh;
    int blk = blockIdx.x;
    // heavy-first mapping: x2 classes (80..99, ~1260 cands) get blockIdx 0..79
    int b, c;
    if (blk < BATCH * 20) { b = blk / 20; c = 80 + (blk - b * 20); }
    else { int z = blk - BATCH * 20; b = z / 80; c = z - b * 80; }
    int bucket = b * NCLS + c;
    int t = threadIdx.x;
    if (t == 0) { lcnt = 0; mSh = 0; }
    __syncthreads();
    // ---- compaction: scan the batch's key array (coalesced 16B loads)
    const ulonglong2* rk2 = (const ulonglong2*)(rowKey + (size_t)b * NROW);
    for (int i = t; i < NROW / 2; i += 256) {
        ulonglong2 kk = rk2[i];
        bool m0 = (kk.x != 0ULL) && ((int)(kk.x & 0xFF) == c);
        bool m1 = (kk.y != 0ULL) && ((int)(kk.y & 0xFF) == c);
        u64 mb0 = __ballot(m0);
        u64 mb1 = __ballot(m1);
        if ((mb0 | mb1) != 0ULL) {
            int lane = t & 63;
            int basew;
            if (lane == 0) basew = atomicAdd(&lcnt, __popcll(mb0) + __popcll(mb1));
            basew = __shfl(basew, 0, 64);
            u64 below = (1ULL << lane) - 1ULL;
            if (m0) {
                int pos = basew + __popcll(mb0 & below);
                if (pos < CAPB) sk[pos] = kk.x;
            }
            if (m1) {
                int pos = basew + __popcll(mb0) + __popcll(mb1 & below);
                if (pos < CAPB) sk[pos] = kk.y;
            }
        }
    }
    __syncthreads();
    int cnt0 = min(lcnt, CAPB);
    if (cnt0 == 0) { if (t == 0) accCnt[bucket] = 0; return; }
    // ---- pad + bitonic sort (descending; keys unique, 0 = -inf sentinel)
    int L = 1; while (L < cnt0) L <<= 1;
    for (int i = cnt0 + t; i < L; i += 256) sk[i] = 0ULL;
    __syncthreads();
    for (int k = 2; k <= L; k <<= 1) {
        for (int j = k >> 1; j > 0; j >>= 1) {
            for (int i = t; i < L; i += 256) {
                int pp = i ^ j;
                if (pp > i) {
                    bool dir = ((i & k) == 0);
                    u64 a = sk[i], bb = sk[pp];
                    bool sw = dir ? (a < bb) : (a > bb);
                    if (sw) { sk[i] = bb; sk[pp] = a; }
                }
            }
            __syncthreads();
        }
    }
    // ---- stage quantized nms-boxes: fl(box + c*7680) exactly as the reference
    float off = (float)c * MAXWH;
    for (int i = t; i < cnt0; i += 256) {
        u64 k = sk[i];
        int n = 0xFFFF ^ (int)((k >> 8) & 0xFFFF);
        float4 v = boxes4[b * NROW + n];
        v.x += off; v.y += off; v.z += off; v.w += off;
        cQ[i] = v;
    }
    __syncthreads();
    // ---- greedy: 256-wide chunks, wave-ordered resolve
    int lane = t & 63, wid = t >> 6;
    for (int base = 0; base < cnt0; base += 256) {
        int m0 = mSh;                     // ordered by barrier at loop top/end
        if (m0 >= 100) break;             // uniform
        int j = base + t;
        bool alive = (j < cnt0);
        float4 a = make_float4(0.f, 0.f, 0.f, 0.f);
        float aA = 0.f; u64 myKey = 0ULL;
        if (alive) { a = cQ[j]; myKey = sk[j]; aA = (a.z - a.x) * (a.w - a.y); }
        // phase 1: all 4 waves suppress vs accQ[0..m0), unroll 8, early-out per 8
        int k2 = 0;
        while (k2 < m0) {
            if (__ballot(alive) == 0ULL) break;
            int lim = min(k2 + 8, m0);
            for (; k2 < lim; ++k2) {
                float4 q = accQ[k2];                       // b128 broadcast
                float qa = (q.z - q.x) * (q.w - q.y);
                float xx1 = fmaxf(a.x, q.x), yy1 = fmaxf(a.y, q.y);
                float xx2 = fminf(a.z, q.z), yy2 = fminf(a.w, q.w);
                float inter = fmaxf(xx2 - xx1, 0.f) * fmaxf(yy2 - yy1, 0.f);
                if (inter / (qa + aA - inter + 1e-9f) > IOU_T) alive = false;
            }
        }
        __syncthreads();
        // phase 2: wave-by-wave ordered resolve
        for (int w = 0; w < 4; ++w) {
            if (wid == w) {
                int mNow = mSh;
                for (int k2d = m0; k2d < mNow; ++k2d) {    // delta from earlier waves
                    if (__ballot(alive) == 0ULL) break;
                    float4 q = accQ[k2d];
                    float qa = (q.z - q.x) * (q.w - q.y);
                    float xx1 = fmaxf(a.x, q.x), yy1 = fmaxf(a.y, q.y);
                    float xx2 = fminf(a.z, q.z), yy2 = fminf(a.w, q.w);
                    float inter = fmaxf(xx2 - xx1, 0.f) * fmaxf(yy2 - yy1, 0.f);
                    if (inter / (qa + aA - inter + 1e-9f) > IOU_T) alive = false;
                }
                u64 av = __ballot(alive);
                int m = mNow;
                while (av != 0ULL && m < 100) {
                    int f = __builtin_ctzll(av);
                    float qx = __shfl(a.x, f, 64), qy = __shfl(a.y, f, 64);
                    float qz = __shfl(a.z, f, 64), qw = __shfl(a.w, f, 64);
                    if (lane == f) {
                        accQ[m] = a;
                        accKey[(size_t)bucket * 100 + m] = myKey;
                        alive = false;
                    }
                    ++m;
                    if (alive) {          // all remaining alive lanes are > f
                        float qa = (qz - qx) * (qw - qy);
                        float xx1 = fmaxf(a.x, qx), yy1 = fmaxf(a.y, qy);
                        float xx2 = fminf(a.z, qz), yy2 = fminf(a.w, qw);
                        float inter = fmaxf(xx2 - xx1, 0.f) * fmaxf(yy2 - yy1, 0.f);
                        if (inter / (qa + aA - inter + 1e-9f) > IOU_T) alive = false;
                    }
                    av = __ballot(alive);
                }
                if (lane == 0) mSh = m;
            }
            __syncthreads();
        }
    }
    __syncthreads();
    if (t == 0) accCnt[bucket] = mSh;
}

// ---------------- Kernel D: per-batch merge, single-wave shuffle tournament
__global__ __launch_bounds__(256) void k_merge(const float4* __restrict__ boxes4,
                                               const u64* __restrict__ accKey,
                                               const int* __restrict__ accCnt,
                                               float* __restrict__ out) {
    __shared__ u64 keys[NCLS * 100];      // 80 KB
    __shared__ u64 winKey[100];
    __shared__ int cnts[NCLS];
    int b = blockIdx.x;
    int t = threadIdx.x;
    if (t < NCLS) cnts[t] = accCnt[b * NCLS + t];
    __syncthreads();
    for (int i = t; i < NCLS * 100; i += 256) {
        int c = i / 100, j = i - c * 100;
        keys[i] = (j < cnts[c]) ? accKey[(size_t)(b * NCLS + c) * 100 + j] : 0ULL;
    }
    __syncthreads();
    if (t < 64) {
        int c0 = 2 * t, c1 = 2 * t + 1;   // lanes 50..63 own no real class
        int h0 = 0, h1 = 0;
        u64 hk0 = (c0 < NCLS && cnts[c0] > 0) ? keys[c0 * 100] : 0ULL;
        u64 hk1 = (c1 < NCLS && cnts[c1] > 0) ? keys[c1 * 100] : 0ULL;
        for (int step = 0; step < 100; ++step) {
            u64 k = (hk0 >= hk1) ? hk0 : hk1;
            for (int o = 1; o < 64; o <<= 1) {
                u64 ok = __shfl_xor(k, o, 64);
                if (ok > k) k = ok;
            }
            if (t == 0) winKey[step] = k;
            if (k != 0ULL) {
                int cls = (int)(k & 0xFF);
                if (cls == c0)      { ++h0; hk0 = (h0 < cnts[c0]) ? keys[c0 * 100 + h0] : 0ULL; }
                else if (cls == c1) { ++h1; hk1 = (h1 < cnts[c1]) ? keys[c1 * 100 + h1] : 0ULL; }
            }
        }
    }
    __syncthreads();
    if (t < 100) {
        u64 k = winKey[t];
        float* o7 = out + (size_t)(b * 100 + t) * 7;
        if (k == 0ULL) {
            o7[0] = -1.0f;
            o7[1] = 0.0f; o7[2] = 0.0f; o7[3] = 0.0f;
            o7[4] = 0.0f; o7[5] = 0.0f; o7[6] = 0.0f;
        } else {
            int n = 0xFFFF ^ (int)((k >> 8) & 0xFFFF);
            int cid = (int)(k & 0xFF);
            float4 bx = boxes4[b * NROW + n];
            o7[0] = (float)b;
            o7[1] = bx.x; o7[2] = bx.y; o7[3] = bx.z; o7[4] = bx.w;
            o7[5] = (float)cid;
            o7[6] = __uint_as_float((unsigned)(k >> 32));
        }
    }
}

extern "C" void kernel_launch(void* const* d_in, const int* in_sizes, int n_in,
                              void* d_out, int out_size, void* d_ws, size_t ws_size,
                              hipStream_t stream) {
    const float* x1 = (const float*)d_in[0];
    const float* x2 = (const float*)d_in[1];
    float* out = (float*)d_out;

    // workspace (~5.2 MiB): boxes4 | rowKey | accKey | accCnt
    float4* boxes4 = (float4*)d_ws;                          // TOT float4
    u64* rowKey = (u64*)(boxes4 + TOT);                      // TOT u64
    u64* accKey = rowKey + TOT;                              // 400*100 u64
    int* accCnt = (int*)(accKey + (size_t)BATCH * NCLS * 100);  // 400 (always written)

    int rowBlocks = BATCH * X1_SPB + BATCH * X2_SPB;         // 1576 + 396 = 1972
    k_rows<<<rowBlocks, 256, 0, stream>>>(x1, x2, boxes4, rowKey);
    k_nms<<<BATCH * NCLS, 256, 0, stream>>>(boxes4, rowKey, accKey, accCnt);
    k_merge<<<BATCH, 256, 0, stream>>>(boxes4, accKey, accCnt, out);
}

// Round 8
// 160.940 us; speedup vs baseline: 1.2132x; 1.2132x over previous
//
#include <hip/hip_runtime.h>
#include <stdint.h>

#pragma clang fp contract(off)   // pin IEEE single-rounding: must match numpy ref bit-exactly

#define BATCH 4
#define N1 25200
#define NROW 50400           // N1 + N2
#define NCLS 100
#define TOT (BATCH*NROW)     // 201600
#define CAPB 2048
#define SCORE_T 0.25f
#define IOU_T 0.45f
#define MAXWH 7680.0f

#define X1_SLAB 64
#define X1_SPB 394           // ceil(25200/64)
#define X2_SLAB 256
#define X2_SPB 99            // ceil(25200/256)

typedef unsigned long long u64;

// key = score_bits(63..32) | (n^0xFFFF)(23..8) | catid(7..0)
// descending key order == (score desc, n asc); catid bits never decide
__device__ __forceinline__ u64 pack_key(unsigned sb, int n, int cid) {
    return ((u64)sb << 32) | ((u64)(unsigned)((n ^ 0xFFFF) & 0xFFFF) << 8) | (u64)(unsigned)cid;
}

// ---------------- Kernel A: decode + argmax -> boxes4 + one packed key per row.
__global__ __launch_bounds__(256) void k_rows(const float* __restrict__ x1,
                                              const float* __restrict__ x2,
                                              float4* __restrict__ boxes4,
                                              u64* __restrict__ rowKey) {
    __shared__ float4 ld4[1600];          // 25.6 KB (>= 64*85 and 256*25 floats)
    float* ld = (float*)ld4;
    int blk = blockIdx.x;
    int t = threadIdx.x;
    const int NX1 = BATCH * X1_SPB;
    if (blk < NX1) {
        int b = blk / X1_SPB, s = blk - b * X1_SPB;
        int r0 = s * X1_SLAB;
        int nr = min(X1_SLAB, N1 - r0);
        const float4* src = (const float4*)(x1 + ((size_t)b * N1 + r0) * 85);
        int count4 = (nr * 85) >> 2;      // nr in {64,48} -> divisible by 4
        for (int i = t; i < count4; i += 256) ld4[i] = src[i];
        __syncthreads();
        int row = t >> 2, sub = t & 3;
        if (row < nr) {
            const float* p = ld + row * 85;
            float conf = p[4];
            u64 key = 0ULL;
            int base = sub * 20;
            for (int c = 0; c < 20; ++c) {
                int j = base + c;
                float v = p[5 + j] * conf;
                u64 kk = ((u64)__float_as_uint(v) << 32) | (unsigned)~(unsigned)j;
                if (kk > key) key = kk;
            }
            u64 o;
            o = __shfl_xor(key, 1, 64); if (o > key) key = o;
            o = __shfl_xor(key, 2, 64); if (o > key) key = o;
            if (sub == 0) {
                float best = __uint_as_float((unsigned)(key >> 32));
                int bestj = ~(unsigned)key;
                int n = r0 + row;
                int r = b * NROW + n;
                u64 outk = 0ULL;
                if (best >= SCORE_T) {
                    float cx = p[0], cy = p[1], w = p[2], h = p[3];
                    boxes4[r] = make_float4(cx - 0.5f * w, cy - 0.5f * h,
                                            cx + 0.5f * w, cy + 0.5f * h);
                    outk = pack_key((unsigned)(key >> 32), n, bestj);
                }
                rowKey[r] = outk;         // every row written (no stale poison)
            }
        }
    } else {
        int blk2 = blk - NX1;
        int b = blk2 / X2_SPB, s = blk2 - b * X2_SPB;
        int r0 = s * X2_SLAB;
        int nr = min(X2_SLAB, N1 - r0);
        const float4* src = (const float4*)(x2 + ((size_t)b * N1 + r0) * 25);
        int count4 = (nr * 25) >> 2;      // nr in {256,112} -> divisible by 4
        for (int i = t; i < count4; i += 256) ld4[i] = src[i];
        __syncthreads();
        if (t < nr) {
            const float* p = ld + t * 25;
            float conf = p[4];
            float best = 0.0f; int bestj = 0;   // padded classes 0..79 exact zeros
            for (int j2 = 0; j2 < 20; ++j2) {
                float v = p[5 + j2] * conf;
                if (v > best) { best = v; bestj = 80 + j2; }
            }
            int n = N1 + r0 + t;
            int r = b * NROW + n;
            u64 outk = 0ULL;
            if (best >= SCORE_T) {
                float cx = p[0], cy = p[1], w = p[2], h = p[3];
                boxes4[r] = make_float4(cx - 0.5f * w, cy - 0.5f * h,
                                        cx + 0.5f * w, cy + 0.5f * h);
                outk = pack_key(__float_as_uint(best), n, bestj);
            }
            rowKey[r] = outk;
        }
    }
}

// ---------------- Kernel C: per-bucket compact + register-bitonic sort + greedy.
// Sort: thread owns 8 contiguous keys in VGPRs; j<8 in-register, 8<=j<=256 via
// __shfl_xor (no barriers), j>=512 via LDS (2 barriers each, <=3 passes total).
__global__ __launch_bounds__(256) void k_nms(const float4* __restrict__ boxes4,
                                             const u64* __restrict__ rowKey,
                                             u64* __restrict__ accKey,
                                             int* __restrict__ accCnt) {
    __shared__ u64 sk[CAPB];              // 16 KB
    __shared__ float4 cQ[CAPB];           // 32 KB; overlaid as u64 temp[4][512] during compaction
    __shared__ float4 accQ[100];
    __shared__ int wcnt[4];
    int blk = blockIdx.x;
    // heavy-first mapping: x2 classes (80..99, ~1260 cands) get blockIdx 0..79
    int b, c;
    if (blk < BATCH * 20) { b = blk / 20; c = 80 + (blk - b * 20); }
    else { int z = blk - BATCH * 20; b = z / 80; c = z - b * 80; }
    int bucket = b * NCLS + c;
    int t = threadIdx.x;
    int lane = t & 63, wid = t >> 6;

    // ---- compaction: classes>=80 only occur in x2 rows [N1,NROW), <80 in [0,N1)
    int rowBase = (c >= 80) ? N1 : 0;
    const ulonglong2* rk2 = (const ulonglong2*)(rowKey + (size_t)b * NROW + rowBase);
    const int SLICE = 3150;               // 12600 ulonglong2 / 4 waves
    u64* temp = ((u64*)cQ) + wid * 512;   // per-wave region (cap 512 = +11 sigma)
    int wbase = 0;
    for (int i = wid * SLICE + lane; i < (wid + 1) * SLICE; i += 64) {
        ulonglong2 kk = rk2[i];
        bool m0 = (kk.x != 0ULL) && ((int)(kk.x & 0xFF) == c);
        bool m1 = (kk.y != 0ULL) && ((int)(kk.y & 0xFF) == c);
        u64 mb0 = __ballot(m0), mb1 = __ballot(m1);
        u64 below = (1ULL << lane) - 1ULL;
        if (m0) { int p = wbase + __popcll(mb0 & below); if (p < 512) temp[p] = kk.x; }
        if (m1) { int p = wbase + __popcll(mb0) + __popcll(mb1 & below); if (p < 512) temp[p] = kk.y; }
        wbase += __popcll(mb0) + __popcll(mb1);
    }
    if (lane == 0) wcnt[wid] = min(wbase, 512);
    __syncthreads();
    int w0 = wcnt[0], w1 = wcnt[1], w2 = wcnt[2], w3 = wcnt[3];
    int cnt0 = w0 + w1 + w2 + w3;         // <= 2048
    if (cnt0 == 0) { if (t == 0) accCnt[bucket] = 0; return; }
    int myoff = (wid > 0 ? w0 : 0) + (wid > 1 ? w1 : 0) + (wid > 2 ? w2 : 0);
    int mycnt = wcnt[wid];
    for (int i = lane; i < mycnt; i += 64) sk[myoff + i] = temp[i];
    // ---- pad to L (>=512 keeps shuffle passes full-wave)
    int L = 512; while (L < cnt0) L <<= 1;
    for (int i = cnt0 + t; i < L; i += 256) sk[i] = 0ULL;
    __syncthreads();

    // ---- register-blocked bitonic sort, descending (0 = -inf sentinel)
    bool act = (t * 8) < L;
    u64 r[8];
    if (act) {
#pragma unroll
        for (int e = 0; e < 8; ++e) r[e] = sk[t * 8 + e];
    }
    for (int k = 2; k <= L; k <<= 1) {
        for (int j = k >> 1; j > 0; j >>= 1) {
            if (j >= 512) {               // cross-wave: LDS exchange (uniform branch)
                if (act) {
#pragma unroll
                    for (int e = 0; e < 8; ++e) sk[t * 8 + e] = r[e];
                }
                __syncthreads();
                if (act) {
                    bool iAmLo = (t & (j >> 3)) == 0;
                    bool descSeg = (t & (k >> 3)) == 0;
                    bool takeMax = (descSeg == iAmLo);
#pragma unroll
                    for (int e = 0; e < 8; ++e) {
                        u64 u = r[e];
                        u64 v = sk[(t * 8 + e) ^ j];
                        bool uGE = (u >= v);
                        r[e] = (takeMax == uGE) ? u : v;
                    }
                }
                __syncthreads();
            } else if (j >= 8) {          // cross-thread within wave: shuffles
                if (act) {
                    int dt = j >> 3;
                    bool iAmLo = (t & dt) == 0;
                    bool descSeg = (t & (k >> 3)) == 0;   // k>=16 here
                    bool takeMax = (descSeg == iAmLo);
#pragma unroll
                    for (int e = 0; e < 8; ++e) {
                        u64 u = r[e];
                        u64 v = __shfl_xor(u, dt, 64);
                        bool uGE = (u >= v);
                        r[e] = (takeMax == uGE) ? u : v;
                    }
                }
            } else {                      // j in {1,2,4}: in-register
                if (act) {
#pragma unroll
                    for (int e = 0; e < 8; ++e) {
                        if (!(e & j)) {
                            int e2 = e | j;
                            bool descSeg = (k >= 8) ? ((t & (k >> 3)) == 0)
                                                    : ((e & k) == 0);
                            u64 lo = r[e], hi = r[e2];
                            bool sw = descSeg ? (lo < hi) : (lo > hi);
                            if (sw) { r[e] = hi; r[e2] = lo; }
                        }
                    }
                }
            }
        }
    }
    if (act) {
#pragma unroll
        for (int e = 0; e < 8; ++e) sk[t * 8 + e] = r[e];
    }
    __syncthreads();

    // ---- stage quantized nms-boxes: fl(box + c*7680) exactly as the reference
    float off = (float)c * MAXWH;
    for (int i = t; i < cnt0; i += 256) {
        u64 k = sk[i];
        int n = 0xFFFF ^ (int)((k >> 8) & 0xFFFF);
        float4 v = boxes4[b * NROW + n];
        v.x += off; v.y += off; v.z += off; v.w += off;
        cQ[i] = v;
    }
    __syncthreads();

    // ---- greedy: wave 0 only, 64-candidate chunks, zero barriers (round-6 form)
    if (t >= 64) return;
    int m = 0;
    for (int base = 0; base < cnt0 && m < 100; base += 64) {
        int j = base + lane;
        bool alive = (j < cnt0);
        float4 a = make_float4(0.f, 0.f, 0.f, 0.f);
        float aA = 0.f; u64 myKey = 0ULL;
        if (alive) { a = cQ[j]; myKey = sk[j]; aA = (a.z - a.x) * (a.w - a.y); }
        // suppress vs previously-accepted (b128 broadcast reads), early-out per 8
        int k2 = 0;
        while (k2 < m) {
            if (__ballot(alive) == 0ULL) break;
            int lim = min(k2 + 8, m);
            for (; k2 < lim; ++k2) {
                float4 q = accQ[k2];
                float qa = (q.z - q.x) * (q.w - q.y);
                float xx1 = fmaxf(a.x, q.x), yy1 = fmaxf(a.y, q.y);
                float xx2 = fminf(a.z, q.z), yy2 = fminf(a.w, q.w);
                float inter = fmaxf(xx2 - xx1, 0.f) * fmaxf(yy2 - yy1, 0.f);
                if (inter / (qa + aA - inter + 1e-9f) > IOU_T) alive = false;
            }
        }
        // intra-chunk resolve: accept first alive, suppress within chunk
        u64 av = __ballot(alive);
        while (av != 0ULL && m < 100) {
            int f = __builtin_ctzll(av);
            float qx = __shfl(a.x, f, 64), qy = __shfl(a.y, f, 64);
            float qz = __shfl(a.z, f, 64), qw = __shfl(a.w, f, 64);
            if (lane == f) {
                accQ[m] = a;
                accKey[(size_t)bucket * 100 + m] = myKey;
                alive = false;
            }
            ++m;
            if (alive) {                  // all remaining alive lanes are > f
                float qa = (qz - qx) * (qw - qy);
                float xx1 = fmaxf(a.x, qx), yy1 = fmaxf(a.y, qy);
                float xx2 = fminf(a.z, qz), yy2 = fminf(a.w, qw);
                float inter = fmaxf(xx2 - xx1, 0.f) * fmaxf(yy2 - yy1, 0.f);
                if (inter / (qa + aA - inter + 1e-9f) > IOU_T) alive = false;
            }
            av = __ballot(alive);
        }
    }
    if (lane == 0) accCnt[bucket] = m;
}

// ---------------- Kernel D: per-batch merge, single-wave shuffle tournament
__global__ __launch_bounds__(256) void k_merge(const float4* __restrict__ boxes4,
                                               const u64* __restrict__ accKey,
                                               const int* __restrict__ accCnt,
                                               float* __restrict__ out) {
    __shared__ u64 keys[NCLS * 100];      // 80 KB
    __shared__ u64 winKey[100];
    __shared__ int cnts[NCLS];
    int b = blockIdx.x;
    int t = threadIdx.x;
    if (t < NCLS) cnts[t] = accCnt[b * NCLS + t];
    __syncthreads();
    for (int i = t; i < NCLS * 100; i += 256) {
        int c = i / 100, j = i - c * 100;
        keys[i] = (j < cnts[c]) ? accKey[(size_t)(b * NCLS + c) * 100 + j] : 0ULL;
    }
    __syncthreads();
    if (t < 64) {
        int c0 = 2 * t, c1 = 2 * t + 1;   // lanes 50..63 own no real class
        int h0 = 0, h1 = 0;
        u64 hk0 = (c0 < NCLS && cnts[c0] > 0) ? keys[c0 * 100] : 0ULL;
        u64 hk1 = (c1 < NCLS && cnts[c1] > 0) ? keys[c1 * 100] : 0ULL;
        for (int step = 0; step < 100; ++step) {
            u64 k = (hk0 >= hk1) ? hk0 : hk1;
            for (int o = 1; o < 64; o <<= 1) {
                u64 ok = __shfl_xor(k, o, 64);
                if (ok > k) k = ok;
            }
            if (t == 0) winKey[step] = k;
            if (k != 0ULL) {
                int cls = (int)(k & 0xFF);
                if (cls == c0)      { ++h0; hk0 = (h0 < cnts[c0]) ? keys[c0 * 100 + h0] : 0ULL; }
                else if (cls == c1) { ++h1; hk1 = (h1 < cnts[c1]) ? keys[c1 * 100 + h1] : 0ULL; }
            }
        }
    }
    __syncthreads();
    if (t < 100) {
        u64 k = winKey[t];
        float* o7 = out + (size_t)(b * 100 + t) * 7;
        if (k == 0ULL) {
            o7[0] = -1.0f;
            o7[1] = 0.0f; o7[2] = 0.0f; o7[3] = 0.0f;
            o7[4] = 0.0f; o7[5] = 0.0f; o7[6] = 0.0f;
        } else {
            int n = 0xFFFF ^ (int)((k >> 8) & 0xFFFF);
            int cid = (int)(k & 0xFF);
            float4 bx = boxes4[b * NROW + n];
            o7[0] = (float)b;
            o7[1] = bx.x; o7[2] = bx.y; o7[3] = bx.z; o7[4] = bx.w;
            o7[5] = (float)cid;
            o7[6] = __uint_as_float((unsigned)(k >> 32));
        }
    }
}

extern "C" void kernel_launch(void* const* d_in, const int* in_sizes, int n_in,
                              void* d_out, int out_size, void* d_ws, size_t ws_size,
                              hipStream_t stream) {
    const float* x1 = (const float*)d_in[0];
    const float* x2 = (const float*)d_in[1];
    float* out = (float*)d_out;

    // workspace (~5.2 MiB): boxes4 | rowKey | accKey | accCnt
    float4* boxes4 = (float4*)d_ws;                          // TOT float4
    u64* rowKey = (u64*)(boxes4 + TOT);                      // TOT u64
    u64* accKey = rowKey + TOT;                              // 400*100 u64
    int* accCnt = (int*)(accKey + (size_t)BATCH * NCLS * 100);  // 400 (always written)

    int rowBlocks = BATCH * X1_SPB + BATCH * X2_SPB;         // 1576 + 396 = 1972
    k_rows<<<rowBlocks, 256, 0, stream>>>(x1, x2, boxes4, rowKey);
    k_nms<<<BATCH * NCLS, 256, 0, stream>>>(boxes4, rowKey, accKey, accCnt);
    k_merge<<<BATCH, 256, 0, stream>>>(boxes4, accKey, accCnt, out);
}